// Round 6
// baseline (326.776 us; speedup 1.0000x reference)
//
#include <hip/hip_runtime.h>
#include <hip/hip_bf16.h>

#define FIN 256
#define HID 64
#define EMB 2
#define BKB 9            // bucket = dst >> 9 (512 nodes per bucket)
#define BKSZ 512
#define MAXBK 256        // supports N <= 131072
#define NBLK 256         // blocks for binning passes

typedef __bf16 bf16x8 __attribute__((ext_vector_type(8)));
typedef float  f32x16 __attribute__((ext_vector_type(16)));

// ---- bf16 helpers (RNE) ----
static __device__ __forceinline__ unsigned short f2bf(float f) {
    union { float f; unsigned int u; } v; v.f = f;
    unsigned int u = v.u;
    unsigned int r = (u + 0x7fffu + ((u >> 16) & 1u)) >> 16;
    return (unsigned short)r;
}
static __device__ __forceinline__ float bf2f(unsigned short h) {
    union { unsigned int u; float f; } v; v.u = ((unsigned int)h) << 16;
    return v.f;
}

// ---------------------------------------------------------------------------
__global__ void zero_i_kernel(int* __restrict__ p, long n) {
    long i = (long)blockIdx.x * blockDim.x + threadIdx.x;
    if (i < n) p[i] = 0;
}

// 3-kernel exclusive scan
__global__ void scan1_kernel(const int* __restrict__ cnt, int* __restrict__ offs,
                             int* __restrict__ bsums, int M) {
    __shared__ int s[256];
    int tid = threadIdx.x;
    int i = blockIdx.x * 256 + tid;
    int v = (i < M) ? cnt[i] : 0;
    s[tid] = v;
    __syncthreads();
    for (int off = 1; off < 256; off <<= 1) {
        int t = (tid >= off) ? s[tid - off] : 0;
        __syncthreads();
        s[tid] += t;
        __syncthreads();
    }
    if (i < M) offs[i + 1] = s[tid];
    if (tid == 255) bsums[blockIdx.x] = s[255];
    if (i == 0) offs[0] = 0;
}

__global__ void scan2_kernel(int* __restrict__ bsums, int NB) {
    __shared__ int s[512];
    int tid = threadIdx.x;
    s[tid] = (tid < NB) ? bsums[tid] : 0;
    __syncthreads();
    for (int off = 1; off < 512; off <<= 1) {
        int t = (tid >= off) ? s[tid - off] : 0;
        __syncthreads();
        s[tid] += t;
        __syncthreads();
    }
    if (tid < NB) bsums[tid] = s[tid];
}

__global__ void scan3_kernel(int* __restrict__ offs, const int* __restrict__ bsums, int M) {
    int i = blockIdx.x * 256 + threadIdx.x;
    if (i < M && blockIdx.x > 0) offs[i + 1] += bsums[blockIdx.x - 1];
}

// ---------------------------------------------------------------------------
// Pass A1: per-block histogram of coarse buckets (dst>>9)
__global__ __launch_bounds__(256) void bin_hist_kernel(
        const int* __restrict__ dst, int* __restrict__ counts, int E, int chunk, int NBK) {
    __shared__ int hist[MAXBK];
    int tid = threadIdx.x;
    for (int b = tid; b < NBK; b += 256) hist[b] = 0;
    __syncthreads();
    int e0 = blockIdx.x * chunk, e1 = min(e0 + chunk, E);
    for (int i = e0 + tid; i < e1; i += 256) atomicAdd(&hist[dst[i] >> BKB], 1);
    __syncthreads();
    for (int b = tid; b < NBK; b += 256) counts[b * gridDim.x + blockIdx.x] = hist[b];
}

// Pass A2: scatter packed (src<<9 | dst&511) into per-(bucket,block) runs
__global__ __launch_bounds__(256) void bin_scatter_kernel(
        const int* __restrict__ src, const int* __restrict__ dst,
        const int* __restrict__ offs, unsigned* __restrict__ ebuf,
        int E, int chunk, int NBK) {
    __shared__ int cur[MAXBK];
    int tid = threadIdx.x;
    for (int b = tid; b < NBK; b += 256) cur[b] = offs[b * gridDim.x + blockIdx.x];
    __syncthreads();
    int e0 = blockIdx.x * chunk, e1 = min(e0 + chunk, E);
    for (int i = e0 + tid; i < e1; i += 256) {
        int s = src[i], d = dst[i];
        int b = d >> BKB;
        int pos = atomicAdd(&cur[b], 1);
        ebuf[pos] = ((unsigned)s << BKB) | (unsigned)(d & (BKSZ - 1));
    }
}

// Pass B: one block per bucket -> degree/dinv/rowptr + bucket-local CSR scatter
__global__ __launch_bounds__(256) void build_kernel(
        const unsigned* __restrict__ ebuf, const int* __restrict__ offs,
        int* __restrict__ rowptr, float* __restrict__ dinv, int* __restrict__ csr,
        int N, int E) {
    __shared__ int hist[BKSZ];
    __shared__ int scanb[256];
    __shared__ int cur[BKSZ];
    const int b = blockIdx.x, tid = threadIdx.x;
    const int r0 = offs[b * NBLK];
    const int r1 = offs[(b + 1) * NBLK];
    const int nb0 = b * BKSZ;

    hist[tid] = 0; hist[tid + 256] = 0;
    __syncthreads();
    for (int i = r0 + tid; i < r1; i += 256)
        atomicAdd(&hist[ebuf[i] & (BKSZ - 1u)], 1);
    __syncthreads();

    int h0 = hist[2 * tid], h1 = hist[2 * tid + 1];
    if (nb0 + 2 * tid < N)     dinv[nb0 + 2 * tid]     = rsqrtf((float)h0 + 1.f);
    if (nb0 + 2 * tid + 1 < N) dinv[nb0 + 2 * tid + 1] = rsqrtf((float)h1 + 1.f);
    scanb[tid] = h0 + h1;
    __syncthreads();
    for (int off = 1; off < 256; off <<= 1) {
        int t = (tid >= off) ? scanb[tid - off] : 0;
        __syncthreads();
        scanb[tid] += t;
        __syncthreads();
    }
    int base0 = scanb[tid] - (h0 + h1);
    int o0 = base0, o1 = base0 + h0;
    cur[2 * tid] = o0; cur[2 * tid + 1] = o1;
    if (nb0 + 2 * tid < N)     rowptr[nb0 + 2 * tid]     = r0 + o0;
    if (nb0 + 2 * tid + 1 < N) rowptr[nb0 + 2 * tid + 1] = r0 + o1;
    if (nb0 + BKSZ >= N && tid == 0) rowptr[N] = E;
    __syncthreads();
    for (int i = r0 + tid; i < r1; i += 256) {
        unsigned u = ebuf[i];
        int loc = (int)(u & (BKSZ - 1u));
        int p = atomicAdd(&cur[loc], 1);
        csr[r0 + p] = (int)(u >> BKB);
    }
}

// ---------------------------------------------------------------------------
// h1' = dinv * (x @ W1) via MFMA (bf16 hi/lo split).
// Output in PLANE layout: h1p[plane][node][16], plane = feat>>4 (3.2 MB/plane).
__global__ __launch_bounds__(256) void gemm1_kernel(
        const float* __restrict__ x, const float* __restrict__ W,
        const float* __restrict__ dinv, unsigned short* __restrict__ h1p, int N) {
    __shared__ __align__(16) __bf16 A_hi[2 * 4 * 64 * 8];
    __shared__ __align__(16) __bf16 A_lo[2 * 4 * 64 * 8];
    __shared__ __align__(16) __bf16 B_hi[2 * 4 * 64 * 8];
    __shared__ __align__(16) __bf16 B_lo[2 * 4 * 64 * 8];

    const int tid = threadIdx.x;
    const int base = blockIdx.x * 64;
    const int w = tid >> 6;
    const int l = tid & 63;
    const int mg = w >> 1, ng = w & 1;

    f32x16 acc = {};

    const int r  = tid & 63;
    const int ks = tid >> 6;
    const int rl = r & 31, rh = r >> 5;

    for (int ch = 0; ch < 4; ++ch) {
        const int ck0 = ch * 64;
        __syncthreads();
        {
            int row = base + r;
            float f[16];
            if (row < N) {
                const float* xp = &x[(size_t)row * FIN + ck0 + ks * 16];
                float4 v0 = *(const float4*)(xp + 0);
                float4 v1 = *(const float4*)(xp + 4);
                float4 v2 = *(const float4*)(xp + 8);
                float4 v3 = *(const float4*)(xp + 12);
                f[0]=v0.x; f[1]=v0.y; f[2]=v0.z; f[3]=v0.w;
                f[4]=v1.x; f[5]=v1.y; f[6]=v1.z; f[7]=v1.w;
                f[8]=v2.x; f[9]=v2.y; f[10]=v2.z; f[11]=v2.w;
                f[12]=v3.x; f[13]=v3.y; f[14]=v3.z; f[15]=v3.w;
            } else {
                #pragma unroll
                for (int q = 0; q < 16; ++q) f[q] = 0.f;
            }
            bf16x8 ha, hb, la, lb;
            #pragma unroll
            for (int q = 0; q < 8; ++q) {
                __bf16 h0 = (__bf16)f[q];
                ha[q] = h0; la[q] = (__bf16)(f[q] - (float)h0);
                __bf16 h1v = (__bf16)f[q + 8];
                hb[q] = h1v; lb[q] = (__bf16)(f[q + 8] - (float)h1v);
            }
            int ra = ((rh * 4 + ks) * 64 + rl) * 8;
            int rb = ((rh * 4 + ks) * 64 + 32 + rl) * 8;
            *(bf16x8*)&A_hi[ra] = ha; *(bf16x8*)&A_hi[rb] = hb;
            *(bf16x8*)&A_lo[ra] = la; *(bf16x8*)&A_lo[rb] = lb;
        }
        {
            const float* wp = &W[(size_t)(ck0 + ks * 16) * HID + r];
            float f[16];
            #pragma unroll
            for (int q = 0; q < 16; ++q) f[q] = wp[q * HID];
            bf16x8 ha, hb, la, lb;
            #pragma unroll
            for (int q = 0; q < 8; ++q) {
                __bf16 h0 = (__bf16)f[q];
                ha[q] = h0; la[q] = (__bf16)(f[q] - (float)h0);
                __bf16 h1v = (__bf16)f[q + 8];
                hb[q] = h1v; lb[q] = (__bf16)(f[q + 8] - (float)h1v);
            }
            int ra = ((rh * 4 + ks) * 64 + rl) * 8;
            int rb = ((rh * 4 + ks) * 64 + 32 + rl) * 8;
            *(bf16x8*)&B_hi[ra] = ha; *(bf16x8*)&B_hi[rb] = hb;
            *(bf16x8*)&B_lo[ra] = la; *(bf16x8*)&B_lo[rb] = lb;
        }
        __syncthreads();

        #pragma unroll
        for (int s = 0; s < 4; ++s) {
            bf16x8 a_h = *(const bf16x8*)&A_hi[((mg * 4 + s) * 64 + l) * 8];
            bf16x8 a_l = *(const bf16x8*)&A_lo[((mg * 4 + s) * 64 + l) * 8];
            bf16x8 b_h = *(const bf16x8*)&B_hi[((ng * 4 + s) * 64 + l) * 8];
            bf16x8 b_l = *(const bf16x8*)&B_lo[((ng * 4 + s) * 64 + l) * 8];
            acc = __builtin_amdgcn_mfma_f32_32x32x16_bf16(a_h, b_h, acc, 0, 0, 0);
            acc = __builtin_amdgcn_mfma_f32_32x32x16_bf16(a_h, b_l, acc, 0, 0, 0);
            acc = __builtin_amdgcn_mfma_f32_32x32x16_bf16(a_l, b_h, acc, 0, 0, 0);
        }
    }

    const int col = l & 31;
    const int rbase = 4 * (l >> 5);
    const int plane = ng * 2 + (col >> 4);   // feat = ng*32+col; plane = feat>>4
    const int c16 = col & 15;
    #pragma unroll
    for (int reg = 0; reg < 16; ++reg) {
        int row = (reg & 3) + 8 * (reg >> 2) + rbase;
        int node = base + mg * 32 + row;
        if (node < N)
            h1p[((size_t)plane * N + node) * 16 + c16] = f2bf(acc[reg] * dinv[node]);
    }
}

// ---------------------------------------------------------------------------
// Aggregation pass over one 16-feat plane (3.2 MB -> L2-resident gathers).
// Thread group = 4 lanes per node (ushort4 = 4 feats each); 16 nodes/wave.
__global__ __launch_bounds__(256) void agg1_pass_kernel(
        const int* __restrict__ rowptr, const int* __restrict__ csr,
        const unsigned short* __restrict__ h1plane,   // [N][16] bf16
        float* __restrict__ pagg,                     // [N][16] fp32 partial
        int N) {
    long t = (long)blockIdx.x * blockDim.x + threadIdx.x;
    int n = (int)(t >> 2);
    int li = (int)(t & 3);
    if (n >= N) return;
    const ushort4* hp = (const ushort4*)h1plane;

    ushort4 sl = hp[(size_t)n * 4 + li];   // self term (h1' pre-scaled by dinv[src])
    float v0 = bf2f(sl.x), v1 = bf2f(sl.y), v2 = bf2f(sl.z), v3 = bf2f(sl.w);

    int j0 = rowptr[n], j1 = rowptr[n + 1];
    int j = j0;
    for (; j + 3 < j1; j += 4) {
        int s0 = csr[j], s1 = csr[j + 1], s2 = csr[j + 2], s3 = csr[j + 3];
        ushort4 g0 = hp[(size_t)s0 * 4 + li];
        ushort4 g1 = hp[(size_t)s1 * 4 + li];
        ushort4 g2 = hp[(size_t)s2 * 4 + li];
        ushort4 g3 = hp[(size_t)s3 * 4 + li];
        v0 += bf2f(g0.x) + bf2f(g1.x) + bf2f(g2.x) + bf2f(g3.x);
        v1 += bf2f(g0.y) + bf2f(g1.y) + bf2f(g2.y) + bf2f(g3.y);
        v2 += bf2f(g0.z) + bf2f(g1.z) + bf2f(g2.z) + bf2f(g3.z);
        v3 += bf2f(g0.w) + bf2f(g1.w) + bf2f(g2.w) + bf2f(g3.w);
    }
    for (; j < j1; ++j) {
        ushort4 g = hp[(size_t)csr[j] * 4 + li];
        v0 += bf2f(g.x); v1 += bf2f(g.y); v2 += bf2f(g.z); v3 += bf2f(g.w);
    }
    *(float4*)&pagg[((size_t)n * 4 + li) * 4] = make_float4(v0, v1, v2, v3);
}

// ---------------------------------------------------------------------------
// Finish layer 1: dinv*agg + b1, ReLU, (64->2) W2 -> h2' = dinv*h2.
// 16 lanes per node, lane li covers feats [li*4, li*4+4) from plane li>>2.
__global__ __launch_bounds__(256) void finish1_kernel(
        const float* __restrict__ pagg,     // [4][N][16] fp32
        const float* __restrict__ dinv, const float* __restrict__ b1,
        const float* __restrict__ W2, float* __restrict__ h2, int N) {
    long t = (long)blockIdx.x * blockDim.x + threadIdx.x;
    int n = (int)(t >> 4);
    int li = threadIdx.x & 15;
    if (n >= N) return;
    int plane = li >> 2, off = (li & 3) * 4;
    float4 v = *(const float4*)&pagg[((size_t)plane * N + n) * 16 + off];
    float di = dinv[n];
    const float4 b4 = *(const float4*)&b1[li * 4];
    float v0 = fmaxf(di * v.x + b4.x, 0.f);
    float v1 = fmaxf(di * v.y + b4.y, 0.f);
    float v2 = fmaxf(di * v.z + b4.z, 0.f);
    float v3 = fmaxf(di * v.w + b4.w, 0.f);

    const float4* W24 = (const float4*)W2;
    float4 wa = W24[li * 2], wb = W24[li * 2 + 1];
    float r0 = v0 * wa.x + v1 * wa.z + v2 * wb.x + v3 * wb.z;
    float r1 = v0 * wa.y + v1 * wa.w + v2 * wb.y + v3 * wb.w;
    #pragma unroll
    for (int o = 1; o < 16; o <<= 1) {
        r0 += __shfl_xor(r0, o);
        r1 += __shfl_xor(r1, o);
    }
    if (li == 0) *(float2*)&h2[(size_t)n * EMB] = make_float2(r0 * di, r1 * di);
}

// ---------------------------------------------------------------------------
// Fused layer-2 CSR gather (h2' is 800 KB -> L2-resident) + b2 + mean pool.
__global__ __launch_bounds__(256) void agg2_pool_kernel(
        const int* __restrict__ rowptr, const int* __restrict__ csr,
        const float* __restrict__ h2,
        const float* __restrict__ dinv, const float* __restrict__ b2,
        const int* __restrict__ batch,
        float* __restrict__ sums, float* __restrict__ cntf, int N) {
    int n = blockIdx.x * blockDim.x + threadIdx.x;
    int lane = threadIdx.x & 63;
    const float2* h2v = (const float2*)h2;
    float v0 = 0.f, v1 = 0.f, c = 0.f;
    int g = -1;
    if (n < N) {
        float di = dinv[n];
        float2 hs = h2v[n];
        v0 = hs.x; v1 = hs.y;
        int j0 = rowptr[n], j1 = rowptr[n + 1];
        int j = j0;
        for (; j + 3 < j1; j += 4) {
            int s0 = csr[j], s1 = csr[j + 1], s2 = csr[j + 2], s3 = csr[j + 3];
            float2 a = h2v[s0], b = h2v[s1], cc = h2v[s2], d = h2v[s3];
            v0 += a.x + b.x + cc.x + d.x;
            v1 += a.y + b.y + cc.y + d.y;
        }
        for (; j < j1; ++j) {
            float2 hv = h2v[csr[j]];
            v0 += hv.x; v1 += hv.y;
        }
        v0 = di * v0 + b2[0];
        v1 = di * v1 + b2[1];
        g = batch[n];
        c = 1.f;
    }
    #pragma unroll
    for (int off = 1; off < 64; off <<= 1) {
        int gg = __shfl_up(g, off);
        float t0 = __shfl_up(v0, off);
        float t1 = __shfl_up(v1, off);
        float tc = __shfl_up(c, off);
        if (lane >= off && gg == g) { v0 += t0; v1 += t1; c += tc; }
    }
    int gn = __shfl_down(g, 1);
    if (g >= 0 && (lane == 63 || gn != g)) {
        atomicAdd(&sums[g * EMB + 0], v0);
        atomicAdd(&sums[g * EMB + 1], v1);
        atomicAdd(&cntf[g], c);
    }
}

__global__ void final_kernel(const float* __restrict__ sums, const float* __restrict__ cntf,
                             float* __restrict__ out, int G) {
    int g = blockIdx.x * blockDim.x + threadIdx.x;
    if (g >= G) return;
    float c = fmaxf(cntf[g], 1.0f);
    out[g * EMB + 0] = sums[g * EMB + 0] / c;
    out[g * EMB + 1] = sums[g * EMB + 1] / c;
}

// ---------------------------------------------------------------------------
extern "C" void kernel_launch(void* const* d_in, const int* in_sizes, int n_in,
                              void* d_out, int out_size, void* d_ws, size_t ws_size,
                              hipStream_t stream) {
    const float* x     = (const float*)d_in[0];
    const int*   ei    = (const int*)d_in[1];
    const int*   batch = (const int*)d_in[2];
    const float* W1    = (const float*)d_in[3];
    const float* b1    = (const float*)d_in[4];
    const float* W2    = (const float*)d_in[5];
    const float* b2    = (const float*)d_in[6];
    float* out = (float*)d_out;

    const int N = in_sizes[0] / FIN;   // 100000
    const int E = in_sizes[1] / 2;     // 1600000
    const int G = out_size / EMB;      // 512
    const int* src = ei;
    const int* dst = ei + E;

    const int NBK = (N + BKSZ - 1) / BKSZ;   // 196 coarse buckets
    const int M = NBK * NBLK;
    const int NBs = (M + 255) / 256;
    const int chunk = (E + NBLK - 1) / NBLK;

    // ---- workspace layout ----
    char* p = (char*)d_ws;
    auto take = [&](size_t bytes) { char* r = p; p += (bytes + 15) & ~(size_t)15; return r; };
    int*      counts = (int*)take(sizeof(int) * M);
    int*      offs   = (int*)take(sizeof(int) * (M + 1));
    int*      bsums  = (int*)take(sizeof(int) * 512);
    unsigned* ebuf   = (unsigned*)take(sizeof(unsigned) * E);
    int*      csr    = (int*)take(sizeof(int) * E);
    int*      rowptr = (int*)take(sizeof(int) * (N + 1));
    float*    dinv   = (float*)take(sizeof(float) * N);
    unsigned short* h1p = (unsigned short*)take(sizeof(unsigned short) * (size_t)N * HID);
    float*    pagg   = (float*)take(sizeof(float) * (size_t)N * HID);
    float*    h2     = (float*)take(sizeof(float) * (size_t)N * EMB);
    float*    sums   = (float*)take(sizeof(float) * G * EMB);
    float*    cntf   = (float*)take(sizeof(float) * G);

    // 1. zero pool accumulators
    zero_i_kernel<<<(3 * G + 255) / 256, 256, 0, stream>>>((int*)sums, 3L * G);
    // 2. CSR build
    bin_hist_kernel<<<NBLK, 256, 0, stream>>>(dst, counts, E, chunk, NBK);
    scan1_kernel<<<NBs, 256, 0, stream>>>(counts, offs, bsums, M);
    scan2_kernel<<<1, 512, 0, stream>>>(bsums, NBs);
    scan3_kernel<<<NBs, 256, 0, stream>>>(offs, bsums, M);
    bin_scatter_kernel<<<NBLK, 256, 0, stream>>>(src, dst, offs, ebuf, E, chunk, NBK);
    build_kernel<<<NBK, 256, 0, stream>>>(ebuf, offs, rowptr, dinv, csr, N, E);
    // 3. h1' = dinv * (x @ W1), plane layout
    gemm1_kernel<<<(N + 63) / 64, 256, 0, stream>>>(x, W1, dinv, h1p, N);
    // 4. plane-partitioned aggregation (L2-resident gathers), then finish
    {
        int blocks = (int)(((long)N * 4 + 255) / 256);
        for (int pl = 0; pl < 4; ++pl) {
            agg1_pass_kernel<<<blocks, 256, 0, stream>>>(
                rowptr, csr, h1p + (size_t)pl * N * 16, pagg + (size_t)pl * N * 16, N);
        }
        finish1_kernel<<<(int)(((long)N * 16 + 255) / 256), 256, 0, stream>>>(
            pagg, dinv, b1, W2, h2, N);
    }
    // 5. fused agg2 + pool
    agg2_pool_kernel<<<(N + 255) / 256, 256, 0, stream>>>(
        rowptr, csr, h2, dinv, b2, batch, sums, cntf, N);
    final_kernel<<<(G + 255) / 256, 256, 0, stream>>>(sums, cntf, out, G);
}

// Round 7
// 296.477 us; speedup vs baseline: 1.1022x; 1.1022x over previous
//
#include <hip/hip_runtime.h>
#include <hip/hip_bf16.h>

#define FIN 256
#define HID 64
#define EMB 2
#define BKB 9            // bucket = dst >> 9 (512 nodes per bucket)
#define BKSZ 512
#define MAXBK 256        // supports N <= 131072
#define NBLK 256         // blocks for binning passes

typedef __bf16 bf16x8 __attribute__((ext_vector_type(8)));
typedef float  f32x16 __attribute__((ext_vector_type(16)));

// ---- bf16 helpers (RNE) ----
static __device__ __forceinline__ unsigned short f2bf(float f) {
    union { float f; unsigned int u; } v; v.f = f;
    unsigned int u = v.u;
    unsigned int r = (u + 0x7fffu + ((u >> 16) & 1u)) >> 16;
    return (unsigned short)r;
}
static __device__ __forceinline__ float bf2f(unsigned short h) {
    union { unsigned int u; float f; } v; v.u = ((unsigned int)h) << 16;
    return v.f;
}

// ---------------------------------------------------------------------------
// Pass A1: per-block histogram of coarse buckets (dst>>9) -> counts[bucket][block]
__global__ __launch_bounds__(256) void bin_hist_kernel(
        const int* __restrict__ dst, int* __restrict__ counts, int E, int chunk, int NBK) {
    __shared__ int hist[MAXBK];
    int tid = threadIdx.x;
    for (int b = tid; b < NBK; b += 256) hist[b] = 0;
    __syncthreads();
    int e0 = blockIdx.x * chunk, e1 = min(e0 + chunk, E);
    for (int i = e0 + tid; i < e1; i += 256) atomicAdd(&hist[dst[i] >> BKB], 1);
    __syncthreads();
    for (int b = tid; b < NBK; b += 256) counts[b * gridDim.x + blockIdx.x] = hist[b];
}

// Scan 1/2: per-bucket exclusive scan of its 256 per-block counts (in place)
// + bucket total. One block per bucket.
__global__ __launch_bounds__(256) void scan_local_kernel(
        int* __restrict__ counts, int* __restrict__ btot) {
    __shared__ int s[256];
    const int b = blockIdx.x, tid = threadIdx.x;
    int v = counts[b * NBLK + tid];
    s[tid] = v;
    __syncthreads();
    for (int off = 1; off < 256; off <<= 1) {
        int t = (tid >= off) ? s[tid - off] : 0;
        __syncthreads();
        s[tid] += t;
        __syncthreads();
    }
    counts[b * NBLK + tid] = s[tid] - v;   // exclusive within bucket
    if (tid == 255) btot[b] = s[255];
}

// Scan 2/2: single block scans bucket totals -> bucketBase[0..NBK]; also zeroes
// the pool accumulators (sums[G*2] + cntf[G]).
__global__ __launch_bounds__(256) void scan_tot_kernel(
        const int* __restrict__ btot, int* __restrict__ bucketBase,
        float* __restrict__ sums, int NBK, int nzero) {
    __shared__ int s[256];
    const int tid = threadIdx.x;
    int v = (tid < NBK) ? btot[tid] : 0;
    s[tid] = v;
    __syncthreads();
    for (int off = 1; off < 256; off <<= 1) {
        int t = (tid >= off) ? s[tid - off] : 0;
        __syncthreads();
        s[tid] += t;
        __syncthreads();
    }
    if (tid < NBK) bucketBase[tid] = s[tid] - v;
    if (tid == NBK - 1) bucketBase[NBK] = s[tid];
    for (int i = tid; i < nzero; i += 256) sums[i] = 0.f;
}

// Pass A2: scatter packed (src<<9 | dst&511) into per-(bucket,block) runs
__global__ __launch_bounds__(256) void bin_scatter_kernel(
        const int* __restrict__ src, const int* __restrict__ dst,
        const int* __restrict__ counts, const int* __restrict__ bucketBase,
        unsigned* __restrict__ ebuf, int E, int chunk, int NBK) {
    __shared__ int cur[MAXBK];
    int tid = threadIdx.x;
    for (int b = tid; b < NBK; b += 256)
        cur[b] = bucketBase[b] + counts[b * gridDim.x + blockIdx.x];
    __syncthreads();
    int e0 = blockIdx.x * chunk, e1 = min(e0 + chunk, E);
    for (int i = e0 + tid; i < e1; i += 256) {
        int s = src[i], d = dst[i];
        int b = d >> BKB;
        int pos = atomicAdd(&cur[b], 1);
        ebuf[pos] = ((unsigned)s << BKB) | (unsigned)(d & (BKSZ - 1));
    }
}

// Pass B: one block per bucket -> degree/dinv/rowptr + bucket-local CSR scatter
__global__ __launch_bounds__(256) void build_kernel(
        const unsigned* __restrict__ ebuf, const int* __restrict__ bucketBase,
        int* __restrict__ rowptr, float* __restrict__ dinv, int* __restrict__ csr,
        int N, int E) {
    __shared__ int hist[BKSZ];
    __shared__ int scanb[256];
    __shared__ int cur[BKSZ];
    const int b = blockIdx.x, tid = threadIdx.x;
    const int r0 = bucketBase[b];
    const int r1 = bucketBase[b + 1];
    const int nb0 = b * BKSZ;

    hist[tid] = 0; hist[tid + 256] = 0;
    __syncthreads();
    for (int i = r0 + tid; i < r1; i += 256)
        atomicAdd(&hist[ebuf[i] & (BKSZ - 1u)], 1);
    __syncthreads();

    int h0 = hist[2 * tid], h1 = hist[2 * tid + 1];
    if (nb0 + 2 * tid < N)     dinv[nb0 + 2 * tid]     = rsqrtf((float)h0 + 1.f);
    if (nb0 + 2 * tid + 1 < N) dinv[nb0 + 2 * tid + 1] = rsqrtf((float)h1 + 1.f);
    scanb[tid] = h0 + h1;
    __syncthreads();
    for (int off = 1; off < 256; off <<= 1) {
        int t = (tid >= off) ? scanb[tid - off] : 0;
        __syncthreads();
        scanb[tid] += t;
        __syncthreads();
    }
    int base0 = scanb[tid] - (h0 + h1);
    int o0 = base0, o1 = base0 + h0;
    cur[2 * tid] = o0; cur[2 * tid + 1] = o1;
    if (nb0 + 2 * tid < N)     rowptr[nb0 + 2 * tid]     = r0 + o0;
    if (nb0 + 2 * tid + 1 < N) rowptr[nb0 + 2 * tid + 1] = r0 + o1;
    if (nb0 + BKSZ >= N && tid == 0) rowptr[N] = E;
    __syncthreads();
    for (int i = r0 + tid; i < r1; i += 256) {
        unsigned u = ebuf[i];
        int loc = (int)(u & (BKSZ - 1u));
        int p = atomicAdd(&cur[loc], 1);
        csr[r0 + p] = (int)(u >> BKB);
    }
}

// ---------------------------------------------------------------------------
// h1' = dinv * (x @ W1) via MFMA (bf16 hi/lo split: xh*wh + xh*wl + xl*wh).
// Block = 64-node x 64-feat tile, 4 waves = four 32x32 quadrants. bf16 store.
__global__ __launch_bounds__(256) void gemm1_kernel(
        const float* __restrict__ x, const float* __restrict__ W,
        const float* __restrict__ dinv, unsigned short* __restrict__ h1b, int N) {
    __shared__ __align__(16) __bf16 A_hi[2 * 4 * 64 * 8];
    __shared__ __align__(16) __bf16 A_lo[2 * 4 * 64 * 8];
    __shared__ __align__(16) __bf16 B_hi[2 * 4 * 64 * 8];
    __shared__ __align__(16) __bf16 B_lo[2 * 4 * 64 * 8];

    const int tid = threadIdx.x;
    const int base = blockIdx.x * 64;
    const int w = tid >> 6;
    const int l = tid & 63;
    const int mg = w >> 1, ng = w & 1;

    f32x16 acc = {};

    const int r  = tid & 63;
    const int ks = tid >> 6;
    const int rl = r & 31, rh = r >> 5;

    for (int ch = 0; ch < 4; ++ch) {
        const int ck0 = ch * 64;
        __syncthreads();
        {
            int row = base + r;
            float f[16];
            if (row < N) {
                const float* xp = &x[(size_t)row * FIN + ck0 + ks * 16];
                float4 v0 = *(const float4*)(xp + 0);
                float4 v1 = *(const float4*)(xp + 4);
                float4 v2 = *(const float4*)(xp + 8);
                float4 v3 = *(const float4*)(xp + 12);
                f[0]=v0.x; f[1]=v0.y; f[2]=v0.z; f[3]=v0.w;
                f[4]=v1.x; f[5]=v1.y; f[6]=v1.z; f[7]=v1.w;
                f[8]=v2.x; f[9]=v2.y; f[10]=v2.z; f[11]=v2.w;
                f[12]=v3.x; f[13]=v3.y; f[14]=v3.z; f[15]=v3.w;
            } else {
                #pragma unroll
                for (int q = 0; q < 16; ++q) f[q] = 0.f;
            }
            bf16x8 ha, hb, la, lb;
            #pragma unroll
            for (int q = 0; q < 8; ++q) {
                __bf16 h0 = (__bf16)f[q];
                ha[q] = h0; la[q] = (__bf16)(f[q] - (float)h0);
                __bf16 h1v = (__bf16)f[q + 8];
                hb[q] = h1v; lb[q] = (__bf16)(f[q + 8] - (float)h1v);
            }
            int ra = ((rh * 4 + ks) * 64 + rl) * 8;
            int rb = ((rh * 4 + ks) * 64 + 32 + rl) * 8;
            *(bf16x8*)&A_hi[ra] = ha; *(bf16x8*)&A_hi[rb] = hb;
            *(bf16x8*)&A_lo[ra] = la; *(bf16x8*)&A_lo[rb] = lb;
        }
        {
            const float* wp = &W[(size_t)(ck0 + ks * 16) * HID + r];
            float f[16];
            #pragma unroll
            for (int q = 0; q < 16; ++q) f[q] = wp[q * HID];
            bf16x8 ha, hb, la, lb;
            #pragma unroll
            for (int q = 0; q < 8; ++q) {
                __bf16 h0 = (__bf16)f[q];
                ha[q] = h0; la[q] = (__bf16)(f[q] - (float)h0);
                __bf16 h1v = (__bf16)f[q + 8];
                hb[q] = h1v; lb[q] = (__bf16)(f[q + 8] - (float)h1v);
            }
            int ra = ((rh * 4 + ks) * 64 + rl) * 8;
            int rb = ((rh * 4 + ks) * 64 + 32 + rl) * 8;
            *(bf16x8*)&B_hi[ra] = ha; *(bf16x8*)&B_hi[rb] = hb;
            *(bf16x8*)&B_lo[ra] = la; *(bf16x8*)&B_lo[rb] = lb;
        }
        __syncthreads();

        #pragma unroll
        for (int s = 0; s < 4; ++s) {
            bf16x8 a_h = *(const bf16x8*)&A_hi[((mg * 4 + s) * 64 + l) * 8];
            bf16x8 a_l = *(const bf16x8*)&A_lo[((mg * 4 + s) * 64 + l) * 8];
            bf16x8 b_h = *(const bf16x8*)&B_hi[((ng * 4 + s) * 64 + l) * 8];
            bf16x8 b_l = *(const bf16x8*)&B_lo[((ng * 4 + s) * 64 + l) * 8];
            acc = __builtin_amdgcn_mfma_f32_32x32x16_bf16(a_h, b_h, acc, 0, 0, 0);
            acc = __builtin_amdgcn_mfma_f32_32x32x16_bf16(a_h, b_l, acc, 0, 0, 0);
            acc = __builtin_amdgcn_mfma_f32_32x32x16_bf16(a_l, b_h, acc, 0, 0, 0);
        }
    }

    const int col = l & 31;
    const int rbase = 4 * (l >> 5);
    #pragma unroll
    for (int reg = 0; reg < 16; ++reg) {
        int row = (reg & 3) + 8 * (reg >> 2) + rbase;
        int node = base + mg * 32 + row;
        if (node < N)
            h1b[(size_t)node * HID + ng * 32 + col] = f2bf(acc[reg] * dinv[node]);
    }
}

// ---------------------------------------------------------------------------
// Fused layer-1 CSR gather (pure sum of pre-scaled h1') + b1 + ReLU + (64->2).
// 4 nodes per wave: 16 lanes/node, lane = 4 feats (ushort4 gather).
__global__ __launch_bounds__(256) void agg1_layer2_kernel(
        const int* __restrict__ rowptr, const int* __restrict__ csr,
        const unsigned short* __restrict__ h1b,
        const float* __restrict__ dinv, const float* __restrict__ b1,
        const float* __restrict__ W2, float* __restrict__ h2, int N) {
    long t = (long)blockIdx.x * blockDim.x + threadIdx.x;
    int n = (int)(t >> 4);
    int li = threadIdx.x & 15;
    if (n >= N) return;
    const ushort4* h14 = (const ushort4*)h1b;

    float di = dinv[n];
    ushort4 sl = h14[(size_t)n * 16 + li];       // self term (h1' pre-scaled)
    float v0 = bf2f(sl.x), v1 = bf2f(sl.y);
    float v2 = bf2f(sl.z), v3 = bf2f(sl.w);

    int j0 = rowptr[n], j1 = rowptr[n + 1];
    int j = j0;
    for (; j + 3 < j1; j += 4) {
        int s0 = csr[j], s1 = csr[j + 1], s2 = csr[j + 2], s3 = csr[j + 3];
        ushort4 g0 = h14[(size_t)s0 * 16 + li];
        ushort4 g1 = h14[(size_t)s1 * 16 + li];
        ushort4 g2 = h14[(size_t)s2 * 16 + li];
        ushort4 g3 = h14[(size_t)s3 * 16 + li];
        v0 += bf2f(g0.x) + bf2f(g1.x) + bf2f(g2.x) + bf2f(g3.x);
        v1 += bf2f(g0.y) + bf2f(g1.y) + bf2f(g2.y) + bf2f(g3.y);
        v2 += bf2f(g0.z) + bf2f(g1.z) + bf2f(g2.z) + bf2f(g3.z);
        v3 += bf2f(g0.w) + bf2f(g1.w) + bf2f(g2.w) + bf2f(g3.w);
    }
    for (; j < j1; ++j) {
        int s = csr[j];
        ushort4 g = h14[(size_t)s * 16 + li];
        v0 += bf2f(g.x); v1 += bf2f(g.y); v2 += bf2f(g.z); v3 += bf2f(g.w);
    }

    const float4 b4 = *(const float4*)&b1[li * 4];
    v0 = fmaxf(di * v0 + b4.x, 0.f); v1 = fmaxf(di * v1 + b4.y, 0.f);
    v2 = fmaxf(di * v2 + b4.z, 0.f); v3 = fmaxf(di * v3 + b4.w, 0.f);

    const float4* W24 = (const float4*)W2;
    float4 wa = W24[li * 2], wb = W24[li * 2 + 1];
    float r0 = v0 * wa.x + v1 * wa.z + v2 * wb.x + v3 * wb.z;
    float r1 = v0 * wa.y + v1 * wa.w + v2 * wb.y + v3 * wb.w;
    #pragma unroll
    for (int off = 1; off < 16; off <<= 1) {
        r0 += __shfl_xor(r0, off);
        r1 += __shfl_xor(r1, off);
    }
    if (li == 0) *(float2*)&h2[(size_t)n * EMB] = make_float2(r0 * di, r1 * di);  // h2' = dinv*h2
}

// ---------------------------------------------------------------------------
// Fused layer-2 CSR gather (pure sum of h2') + b2 + global mean pool.
__global__ __launch_bounds__(256) void agg2_pool_kernel(
        const int* __restrict__ rowptr, const int* __restrict__ csr,
        const float* __restrict__ h2,
        const float* __restrict__ dinv, const float* __restrict__ b2,
        const int* __restrict__ batch,
        float* __restrict__ sums, float* __restrict__ cntf, int N) {
    int n = blockIdx.x * blockDim.x + threadIdx.x;
    int lane = threadIdx.x & 63;
    const float2* h2v = (const float2*)h2;
    float v0 = 0.f, v1 = 0.f, c = 0.f;
    int g = -1;
    if (n < N) {
        float di = dinv[n];
        float2 hs = h2v[n];
        v0 = hs.x; v1 = hs.y;
        int j0 = rowptr[n], j1 = rowptr[n + 1];
        int j = j0;
        for (; j + 3 < j1; j += 4) {
            int s0 = csr[j], s1 = csr[j + 1], s2 = csr[j + 2], s3 = csr[j + 3];
            float2 a = h2v[s0], b = h2v[s1], cc = h2v[s2], d = h2v[s3];
            v0 += a.x + b.x + cc.x + d.x;
            v1 += a.y + b.y + cc.y + d.y;
        }
        for (; j < j1; ++j) {
            float2 hv = h2v[csr[j]];
            v0 += hv.x; v1 += hv.y;
        }
        v0 = di * v0 + b2[0];
        v1 = di * v1 + b2[1];
        g = batch[n];
        c = 1.f;
    }
    #pragma unroll
    for (int off = 1; off < 64; off <<= 1) {
        int gg = __shfl_up(g, off);
        float t0 = __shfl_up(v0, off);
        float t1 = __shfl_up(v1, off);
        float tc = __shfl_up(c, off);
        if (lane >= off && gg == g) { v0 += t0; v1 += t1; c += tc; }
    }
    int gn = __shfl_down(g, 1);
    if (g >= 0 && (lane == 63 || gn != g)) {
        atomicAdd(&sums[g * EMB + 0], v0);
        atomicAdd(&sums[g * EMB + 1], v1);
        atomicAdd(&cntf[g], c);
    }
}

__global__ void final_kernel(const float* __restrict__ sums, const float* __restrict__ cntf,
                             float* __restrict__ out, int G) {
    int g = blockIdx.x * blockDim.x + threadIdx.x;
    if (g >= G) return;
    float c = fmaxf(cntf[g], 1.0f);
    out[g * EMB + 0] = sums[g * EMB + 0] / c;
    out[g * EMB + 1] = sums[g * EMB + 1] / c;
}

// ---------------------------------------------------------------------------
extern "C" void kernel_launch(void* const* d_in, const int* in_sizes, int n_in,
                              void* d_out, int out_size, void* d_ws, size_t ws_size,
                              hipStream_t stream) {
    const float* x     = (const float*)d_in[0];
    const int*   ei    = (const int*)d_in[1];
    const int*   batch = (const int*)d_in[2];
    const float* W1    = (const float*)d_in[3];
    const float* b1    = (const float*)d_in[4];
    const float* W2    = (const float*)d_in[5];
    const float* b2    = (const float*)d_in[6];
    float* out = (float*)d_out;

    const int N = in_sizes[0] / FIN;   // 100000
    const int E = in_sizes[1] / 2;     // 1600000
    const int G = out_size / EMB;      // 512
    const int* src = ei;
    const int* dst = ei + E;

    const int NBK = (N + BKSZ - 1) / BKSZ;   // 196 coarse buckets
    const int chunk = (E + NBLK - 1) / NBLK; // 6250 edges per bin block

    // ---- workspace layout (16 B aligned chunks) ----
    char* p = (char*)d_ws;
    auto take = [&](size_t bytes) { char* r = p; p += (bytes + 15) & ~(size_t)15; return r; };
    int*      counts = (int*)take(sizeof(int) * NBK * NBLK);
    int*      btot   = (int*)take(sizeof(int) * NBK);
    int*      bucketBase = (int*)take(sizeof(int) * (NBK + 1));
    unsigned* ebuf   = (unsigned*)take(sizeof(unsigned) * E);
    int*      csr    = (int*)take(sizeof(int) * E);
    int*      rowptr = (int*)take(sizeof(int) * (N + 1));
    float*    dinv   = (float*)take(sizeof(float) * N);
    unsigned short* h1b = (unsigned short*)take(sizeof(unsigned short) * (size_t)N * HID);
    float*    h2     = (float*)take(sizeof(float) * (size_t)N * EMB);
    float*    sums   = (float*)take(sizeof(float) * G * EMB);
    float*    cntf   = (float*)take(sizeof(float) * G);

    // 1. CSR build: hist -> 2-level bucket scan (+zero sums) -> scatter -> build
    bin_hist_kernel<<<NBLK, 256, 0, stream>>>(dst, counts, E, chunk, NBK);
    scan_local_kernel<<<NBK, 256, 0, stream>>>(counts, btot);
    scan_tot_kernel<<<1, 256, 0, stream>>>(btot, bucketBase, sums, NBK, 3 * G);
    bin_scatter_kernel<<<NBLK, 256, 0, stream>>>(src, dst, counts, bucketBase, ebuf, E, chunk, NBK);
    build_kernel<<<NBK, 256, 0, stream>>>(ebuf, bucketBase, rowptr, dinv, csr, N, E);
    // 2. h1' = dinv * (x @ W1)  (MFMA, bf16 out, row-major)
    gemm1_kernel<<<(N + 63) / 64, 256, 0, stream>>>(x, W1, dinv, h1b, N);
    // 3. fused agg1 + relu + W2 -> h2' = dinv * h2
    agg1_layer2_kernel<<<(int)(((long)N * 16 + 255) / 256), 256, 0, stream>>>(
        rowptr, csr, h1b, dinv, b1, W2, h2, N);
    // 4. fused agg2 + pool, then finalize
    agg2_pool_kernel<<<(N + 255) / 256, 256, 0, stream>>>(
        rowptr, csr, h2, dinv, b2, batch, sums, cntf, N);
    final_kernel<<<(G + 255) / 256, 256, 0, stream>>>(sums, cntf, out, G);
}